// Round 7
// baseline (847.217 us; speedup 1.0000x reference)
//
#include <hip/hip_runtime.h>
#include <hip/hip_bf16.h>
#include <cstddef>
#include <cstdint>

// ---------------------------------------------------------------------------
// Mamba S6 layer. B=4, S=2048, D_MODEL=1024, D_STATE=16, D_CONV=3,
// D_INNER=2048, M=8192.
// Round 7: phase-interleaved 256x256 GEMM (BK=32, 3-slot LDS ring 96 KiB,
// per-phase {ds_read | 2x global_load_lds | 16 MFMA}, counted vmcnt(4),
// setprio) for G1/G3/G4. G6 kept on proven 128^2 kernel as in-run control.
// Scan/conv/transposes unchanged (proven round 4/6). ws 152.5 MiB (proven).
// ---------------------------------------------------------------------------

typedef __hip_bfloat16 bf16;
typedef unsigned int u32;
typedef short short8 __attribute__((ext_vector_type(8)));
typedef float f32x4 __attribute__((ext_vector_type(4)));

#define GLOBAL_AS __attribute__((address_space(1)))
#define LDS_AS    __attribute__((address_space(3)))

__device__ __forceinline__ float bf2f(short s) {
    union { float f; u32 u; } x; x.u = ((u32)(unsigned short)s) << 16; return x.f;
}
__device__ __forceinline__ void store_c(float* p, float v) { *p = v; }
__device__ __forceinline__ void store_c(bf16* p, float v)  { *p = __float2bfloat16(v); }

__device__ __forceinline__ int xcd_swizzle(int orig, int nwg) {
    // bijective when nwg % 8 == 0 (all our grids); identity otherwise
    return ((nwg & 7) == 0) ? ((orig & 7) * (nwg >> 3) + (orig >> 3)) : orig;
}

#define BAR()   do { __builtin_amdgcn_s_barrier(); asm volatile("" ::: "memory"); } while (0)
#define VMW4()  asm volatile("s_waitcnt vmcnt(4)" ::: "memory")
#define VMW0()  asm volatile("s_waitcnt vmcnt(0)" ::: "memory")

// ---------------- 256x256 tile, BK=32, 3-slot ring, phase-interleaved -------
// C[M,N] = A[M,K](bf16) @ Bt[N,K](bf16)^T. 512 thr = 8 waves (2M x 4N).
// Per wave: 128x64 output = 8x4 frags. Per K-tile: 2 phases x 16 MFMA.
// LDS rows are 64 B (32 bf16) = 4 x 16B slots, XOR-swizzled by ((row>>1)&3).
// Requires M%256==0, K%32==0, KT>=2; Bt must have ceil(N/256)*256 rows.
template <typename TC, int MODE>
__global__ __launch_bounds__(512) void gemm256(
    const bf16* __restrict__ A, const bf16* __restrict__ Bt,
    TC* __restrict__ C, int N, int K, int lda, int ldb, int ldc,
    const float* __restrict__ bias)
{
    __shared__ short As[3][256 * 32];   // 48 KiB
    __shared__ short Bs[3][256 * 32];   // 48 KiB

    const int tid  = threadIdx.x;
    const int lane = tid & 63;
    const int wid  = tid >> 6;
    const int wr   = wid >> 2;          // 0..1  (M half)
    const int wc   = wid & 3;           // 0..3  (N quarter)

    const int gx   = gridDim.x;
    const int wgid = xcd_swizzle(blockIdx.y * gx + blockIdx.x, gx * gridDim.y);
    const int m0   = (wgid / gx) * 256;
    const int n0   = (wgid % gx) * 256;

    // staging: thread t covers lds_row = q*128 + (t>>2), 16B slot s4 = t&3.
    // source k pre-swizzled by key ((lds_row>>1)&3) = ((t>>3)&3); dest linear.
    const int st_ks = (((tid & 3) ^ ((tid >> 3) & 3)) << 3);
    const int st_r  = tid >> 2;

    // fragment reads: row = base + (lane&15); key = ((lane&15)>>1)&3
    const int l15   = lane & 15;
    const int slotp = (((lane >> 4) ^ ((l15 >> 1) & 3)) << 3);

    f32x4 acc[8][4] = {};

    const int KT = K >> 5;

    auto STAGE2 = [&](int sl, int kti, int pr) {   // pr 0: A, pr 1: B (2 loads)
        const int kbase = kti << 5;
        #pragma unroll
        for (int q = 0; q < 2; ++q) {
            int lrow = q * 128 + st_r;
            if (pr == 0) {
                const bf16* g = A + (size_t)(m0 + lrow) * lda + kbase + st_ks;
                __builtin_amdgcn_global_load_lds((const GLOBAL_AS u32*)g,
                    (LDS_AS u32*)(&As[sl][q * 4096 + tid * 8]), 16, 0, 0);
            } else {
                const bf16* g = Bt + (size_t)(n0 + lrow) * ldb + kbase + st_ks;
                __builtin_amdgcn_global_load_lds((const GLOBAL_AS u32*)g,
                    (LDS_AS u32*)(&Bs[sl][q * 4096 + tid * 8]), 16, 0, 0);
            }
        }
    };

    // prologue: stage tiles 0 (slot 0) and 1 (slot 1); wait tile 0
    STAGE2(0, 0, 0); STAGE2(0, 0, 1);
    STAGE2(1, 1, 0); STAGE2(1, 1, 1);
    VMW4(); BAR();

    int sl = 0;
    #pragma unroll 1
    for (int kt = 0; kt < KT; ++kt) {
        const bool ds = (kt + 2 < KT);
        const int ns = (sl == 0) ? 2 : sl - 1;       // (sl+2)%3
        short8 a[4], b[4];

        // ---- phase 0: B frags + A frags (rows 0-3), stage next A ----
        #pragma unroll
        for (int j = 0; j < 4; ++j) {
            int row = wc * 64 + j * 16 + l15;
            b[j] = *(const short8*)&Bs[sl][row * 32 + slotp];
        }
        #pragma unroll
        for (int i = 0; i < 4; ++i) {
            int row = wr * 128 + i * 16 + l15;
            a[i] = *(const short8*)&As[sl][row * 32 + slotp];
        }
        if (ds) STAGE2(ns, kt + 2, 0);
        BAR();
        __builtin_amdgcn_s_setprio(1);
        #pragma unroll
        for (int i = 0; i < 4; ++i)
            #pragma unroll
            for (int j = 0; j < 4; ++j)
                acc[i][j] = __builtin_amdgcn_mfma_f32_16x16x32_bf16(
                    a[i], b[j], acc[i][j], 0, 0, 0);
        __builtin_amdgcn_s_setprio(0);
        BAR();

        // ---- phase 1: A frags (rows 4-7), stage next B ----
        #pragma unroll
        for (int i = 0; i < 4; ++i) {
            int row = wr * 128 + (4 + i) * 16 + l15;
            a[i] = *(const short8*)&As[sl][row * 32 + slotp];
        }
        if (ds) STAGE2(ns, kt + 2, 1);
        BAR();
        __builtin_amdgcn_s_setprio(1);
        #pragma unroll
        for (int i = 0; i < 4; ++i)
            #pragma unroll
            for (int j = 0; j < 4; ++j)
                acc[4 + i][j] = __builtin_amdgcn_mfma_f32_16x16x32_bf16(
                    a[i], b[j], acc[4 + i][j], 0, 0, 0);
        __builtin_amdgcn_s_setprio(0);
        if (ds) { VMW4(); } else { VMW0(); }   // tile kt+1 landed (oldest-first)
        BAR();
        sl = (sl == 2) ? 0 : sl + 1;
    }

    // epilogue: C/D layout col=lane&15, row=(lane>>4)*4+reg
    const int cl = lane & 15;
    const int rq = lane >> 4;
    #pragma unroll
    for (int i = 0; i < 8; ++i) {
        #pragma unroll
        for (int j = 0; j < 4; ++j) {
            int gc = n0 + wc * 64 + j * 16 + cl;
            if (gc >= N) continue;
            float bv = (MODE == 1) ? bias[gc] : 0.f;
            #pragma unroll
            for (int f = 0; f < 4; ++f) {
                int gr = m0 + wr * 128 + i * 16 + rq * 4 + f;
                float v = acc[i][j][f];
                if (MODE == 1) {
                    v += bv;
                    v = fmaxf(v, 0.f) + log1pf(__expf(-fabsf(v)));  // softplus
                }
                store_c(&C[(size_t)gr * ldc + gc], v);
            }
        }
    }
}

// ---------------- 128x128 tile GEMM (m97 structure) + XCD swizzle -----------
template <typename TC, int MODE>
__global__ __launch_bounds__(256) void gemm_mfma(
    const bf16* __restrict__ A, const bf16* __restrict__ Bt,
    TC* __restrict__ C, int N, int K, int lda, int ldb, int ldc,
    const float* __restrict__ bias)
{
    __shared__ short As[128 * 64];
    __shared__ short Bs[128 * 64];

    const int tid  = threadIdx.x;
    const int lane = tid & 63;
    const int w    = tid >> 6;
    const int wr   = w >> 1, wc = w & 1;

    const int gx   = gridDim.x;
    const int wgid = xcd_swizzle(blockIdx.y * gx + blockIdx.x, gx * gridDim.y);
    const int m0   = (wgid / gx) * 128;
    const int n0   = (wgid % gx) * 128;

    const int lr = tid >> 3;
    const int s8 = tid & 7;

    f32x4 acc[4][4] = {};

    const int KT = K >> 6;
    for (int kt = 0; kt < KT; ++kt) {
        const int k0 = kt << 6;
        #pragma unroll
        for (int q = 0; q < 4; ++q) {
            int r = q * 32 + lr;
            int ks = (s8 ^ (r & 7)) * 8;
            const bf16* ga = A + (size_t)(m0 + r) * lda + k0 + ks;
            __builtin_amdgcn_global_load_lds((const GLOBAL_AS u32*)ga,
                (LDS_AS u32*)(As + q * 2048 + tid * 8), 16, 0, 0);
        }
        #pragma unroll
        for (int q = 0; q < 4; ++q) {
            int r = q * 32 + lr;
            int ks = (s8 ^ (r & 7)) * 8;
            const bf16* gb = Bt + (size_t)(n0 + r) * ldb + k0 + ks;
            __builtin_amdgcn_global_load_lds((const GLOBAL_AS u32*)gb,
                (LDS_AS u32*)(Bs + q * 2048 + tid * 8), 16, 0, 0);
        }
        __syncthreads();
        #pragma unroll
        for (int s = 0; s < 2; ++s) {
            short8 af[4], bfr[4];
            #pragma unroll
            for (int i = 0; i < 4; ++i) {
                int r = wr * 64 + i * 16 + (lane & 15);
                int slot = ((s << 2) + (lane >> 4)) ^ (r & 7);
                af[i] = *(const short8*)&As[r * 64 + slot * 8];
            }
            #pragma unroll
            for (int j = 0; j < 4; ++j) {
                int r = wc * 64 + j * 16 + (lane & 15);
                int slot = ((s << 2) + (lane >> 4)) ^ (r & 7);
                bfr[j] = *(const short8*)&Bs[r * 64 + slot * 8];
            }
            #pragma unroll
            for (int i = 0; i < 4; ++i)
                #pragma unroll
                for (int j = 0; j < 4; ++j)
                    acc[i][j] = __builtin_amdgcn_mfma_f32_16x16x32_bf16(
                        af[i], bfr[j], acc[i][j], 0, 0, 0);
        }
        __syncthreads();
    }

    const int cl = lane & 15;
    const int rq = lane >> 4;
    #pragma unroll
    for (int i = 0; i < 4; ++i) {
        #pragma unroll
        for (int j = 0; j < 4; ++j) {
            int gc = n0 + wc * 64 + j * 16 + cl;
            if (gc >= N) continue;
            float bv = (MODE == 1) ? bias[gc] : 0.f;
            #pragma unroll
            for (int f = 0; f < 4; ++f) {
                int gr = m0 + wr * 64 + i * 16 + rq * 4 + f;
                float v = acc[i][j][f];
                if (MODE == 1) {
                    v += bv;
                    v = fmaxf(v, 0.f) + log1pf(__expf(-fabsf(v)));
                }
                store_c(&C[(size_t)gr * ldc + gc], v);
            }
        }
    }
}

// wt[n][k] = (bf16) w[k][n]; rows n in [Nsrc,Npad) zero-filled.
__global__ __launch_bounds__(256) void transpose_cast(
    const float* __restrict__ src, bf16* __restrict__ dst,
    int K, int Nsrc, int Npad)
{
    __shared__ float t[32][33];
    int n0 = blockIdx.x * 32, k0 = blockIdx.y * 32;
    int lx = threadIdx.x & 31, ly = threadIdx.x >> 5;
    #pragma unroll
    for (int i = 0; i < 4; ++i) {
        int k = k0 + ly + 8 * i, n = n0 + lx;
        t[ly + 8 * i][lx] = (n < Nsrc) ? src[(size_t)k * Nsrc + n] : 0.f;
    }
    __syncthreads();
    #pragma unroll
    for (int i = 0; i < 4; ++i) {
        int n = n0 + ly + 8 * i;
        if (n < Npad) dst[(size_t)n * K + k0 + lx] = __float2bfloat16(t[lx][ly + 8 * i]);
    }
}

__global__ __launch_bounds__(256) void cast_x_kernel(
    const float* __restrict__ x, bf16* __restrict__ xb)
{
    int i = blockIdx.x * 256 + threadIdx.x;
    float4 v = ((const float4*)x)[i];
    alignas(8) bf16 h[4] = {__float2bfloat16(v.x), __float2bfloat16(v.y),
                            __float2bfloat16(v.z), __float2bfloat16(v.w)};
    ((ushort4*)xb)[i] = *(ushort4*)h;
}

// depthwise conv w=3 SAME per-sequence + bias + SiLU; 8 channels/thread.
__global__ __launch_bounds__(256) void conv_silu(
    const bf16* __restrict__ ur, const float* __restrict__ cw,
    const float* __restrict__ cb, bf16* __restrict__ uc)
{
    int idx = blockIdx.x * 256 + threadIdx.x;
    int d8 = idx & 255;
    int m  = idx >> 8;
    int s  = m & 2047;
    int d0 = d8 << 3;

    short8 z = {0, 0, 0, 0, 0, 0, 0, 0};
    short8 u0 = *(const short8*)&ur[(size_t)m * 2048 + d0];
    short8 um = (s > 0)    ? *(const short8*)&ur[(size_t)(m - 1) * 2048 + d0] : z;
    short8 up = (s < 2047) ? *(const short8*)&ur[(size_t)(m + 1) * 2048 + d0] : z;

    float wv[24];
    #pragma unroll
    for (int q = 0; q < 6; ++q) *(float4*)&wv[q * 4] = ((const float4*)(cw + d0 * 3))[q];
    float bv[8];
    *(float4*)&bv[0] = ((const float4*)(cb + d0))[0];
    *(float4*)&bv[4] = ((const float4*)(cb + d0))[1];

    alignas(16) bf16 o[8];
    #pragma unroll
    for (int i = 0; i < 8; ++i) {
        float acc = bv[i] + wv[i * 3] * bf2f(um[i]) + wv[i * 3 + 1] * bf2f(u0[i])
                  + wv[i * 3 + 2] * bf2f(up[i]);
        float sig = 1.f / (1.f + __expf(-acc));
        o[i] = __float2bfloat16(acc * sig);
    }
    *(short8*)&uc[(size_t)m * 2048 + d0] = *(short8*)o;
}

// ---- chunk-parallel selective scan: NC=16 chunks of L=128 ------------------
// summaries layout: [b][c][n][dl], idx = (((b*16+c)*16+n)<<10) + dl
__global__ __launch_bounds__(256) void scan_partial(
    const float* __restrict__ deltaC,
    const bf16* __restrict__ uc,
    const bf16* __restrict__ xdbl,
    const float* __restrict__ A_log,
    float* __restrict__ hout, float* __restrict__ aprod, int d0)
{
    int dl = blockIdx.x * 256 + threadIdx.x;
    int c  = blockIdx.y;
    int b  = blockIdx.z;
    int d  = d0 + dl;

    float a[16];
    #pragma unroll
    for (int n = 0; n < 16; ++n) a[n] = -__expf(A_log[d * 16 + n]);
    float hl[16] = {};
    float P[16];
    #pragma unroll
    for (int n = 0; n < 16; ++n) P[n] = 1.f;

    size_t mbase = (size_t)b * 2048 + c * 128;
    for (int s = 0; s < 128; ++s) {
        size_t m = mbase + s;
        float dv = deltaC[m * 1024 + dl];
        float uv = bf2f(*(const short*)&uc[m * 2048 + d]);
        const short8* bp = (const short8*)&xdbl[m * 2080 + 2048];
        short8 B0 = bp[0], B1 = bp[1];
        float du = dv * uv;
        #pragma unroll
        for (int n = 0; n < 16; ++n) {
            float al = __expf(dv * a[n]);
            float Bn = bf2f(n < 8 ? B0[n] : B1[n - 8]);
            hl[n] = al * hl[n] + du * Bn;
            P[n] *= al;
        }
    }
    #pragma unroll
    for (int n = 0; n < 16; ++n) {
        int idx = (((b * 16 + c) * 16 + n) << 10) + dl;
        hout[idx]  = hl[n];
        aprod[idx] = P[n];
    }
}

__global__ __launch_bounds__(256) void scan_combine(
    float* hout, const float* __restrict__ aprod)
{
    int dl = blockIdx.x * 256 + threadIdx.x;
    int n  = blockIdx.y;
    int b  = blockIdx.z;
    float H = 0.f;
    for (int c = 0; c < 16; ++c) {
        int idx = (((b * 16 + c) * 16 + n) << 10) + dl;
        float he = hout[idx];
        float Pp = aprod[idx];
        hout[idx] = H;            // h at chunk start
        H = Pp * H + he;
    }
}

__global__ __launch_bounds__(256) void scan_final(
    const float* __restrict__ deltaC,
    const bf16* __restrict__ uc,
    const bf16* __restrict__ xdbl,
    const float* __restrict__ hin,
    const float* __restrict__ A_log, const float* __restrict__ D_param,
    bf16* ygate, int d0)
{
    int dl = blockIdx.x * 256 + threadIdx.x;
    int c  = blockIdx.y;
    int b  = blockIdx.z;
    int d  = d0 + dl;

    float a[16], H[16];
    #pragma unroll
    for (int n = 0; n < 16; ++n) {
        a[n] = -__expf(A_log[d * 16 + n]);
        H[n] = hin[(((b * 16 + c) * 16 + n) << 10) + dl];
    }
    float Dp = D_param[d];
    float hl[16] = {};
    float P[16];
    #pragma unroll
    for (int n = 0; n < 16; ++n) P[n] = 1.f;

    size_t mbase = (size_t)b * 2048 + c * 128;
    float xg_cur = bf2f(*(const short*)&ygate[mbase * 2048 + d]);

    for (int s = 0; s < 128; ++s) {
        size_t m = mbase + s;
        float dv = deltaC[m * 1024 + dl];
        float uv = bf2f(*(const short*)&uc[m * 2048 + d]);
        const short8* bp = (const short8*)&xdbl[m * 2080 + 2048];
        short8 B0 = bp[0], B1 = bp[1], C0 = bp[2], C1 = bp[3];
        float du = dv * uv;
        float y = 0.f;
        #pragma unroll
        for (int n = 0; n < 16; ++n) {
            float al = __expf(dv * a[n]);
            float Bn = bf2f(n < 8 ? B0[n] : B1[n - 8]);
            float Cn = bf2f(n < 8 ? C0[n] : C1[n - 8]);
            hl[n] = al * hl[n] + du * Bn;
            P[n] *= al;
            float ht = fmaf(P[n], H[n], hl[n]);
            y = fmaf(ht, Cn, y);
        }
        float xgv = xg_cur;
        if (s < 127) xg_cur = bf2f(*(const short*)&ygate[(m + 1) * 2048 + d]);
        float sig = 1.f / (1.f + __expf(-xgv));
        float y2 = (y + uv * Dp) * (xgv * sig);
        ygate[m * 2048 + d] = __float2bfloat16(y2);
    }
}

extern "C" void kernel_launch(void* const* d_in, const int* in_sizes, int n_in,
                              void* d_out, int out_size, void* d_ws, size_t ws_size,
                              hipStream_t stream) {
    const float* x    = (const float*)d_in[0];
    const float* w1   = (const float*)d_in[1];   // [1024,4096]
    const float* cw   = (const float*)d_in[2];   // [2048,1,3]
    const float* cb   = (const float*)d_in[3];   // [2048]
    const float* w2   = (const float*)d_in[4];   // [2048,2080]
    const float* w3   = (const float*)d_in[5];   // [2048,2048]
    const float* dtb  = (const float*)d_in[6];   // [2048]
    const float* w4   = (const float*)d_in[7];   // [2048,1024]
    const float* alog = (const float*)d_in[8];   // [2048,16]
    const float* dpar = (const float*)d_in[9];   // [2048]
    float* out = (float*)d_out;

    // ws layout (152.6 MiB, proven):
    //  [0,24):    phase1 xbf(16)+w1t(8); after G1: w2t(9, 2304 rows padded)
    //             + w3t(8) + w4t(4); after G3: summ_h(4)+summ_a(4) overlay w2t
    //  [24,56):   u_raw bf16 -> (after conv) deltaC f32 [8192,1024]
    //  [56,88):   xg bf16 -> y2 in-place (scan C)
    //  [88,120):  uc bf16
    //  [120,152.6): xdbl bf16 [8192,2080]
    const size_t MB = 1u << 20;
    const size_t needed = 120 * MB + (size_t)8192 * 2080 * 2;
    if (ws_size < needed) return;

    char* p = (char*)d_ws;
    bf16*  xbf    = (bf16*)(p);
    bf16*  w1t    = (bf16*)(p + 16 * MB);
    bf16*  u_raw  = (bf16*)(p + 24 * MB);
    bf16*  w2t    = (bf16*)(p);                          // [2304,2048] 9 MiB
    bf16*  w3t    = (bf16*)(p + (size_t)2304 * 2048 * 2);
    bf16*  w4t    = (bf16*)(p + (size_t)2304 * 2048 * 2 + (size_t)2048 * 2048 * 2);
    float* summ_h = (float*)(p);                         // 4 MiB, after G3
    float* summ_a = (float*)(p + 4 * MB);
    float* deltaC = (float*)(p + 24 * MB);
    bf16*  xg     = (bf16*)(p + 56 * MB);
    bf16*  uc     = (bf16*)(p + 88 * MB);
    bf16*  xdbl   = (bf16*)(p + 120 * MB);

    cast_x_kernel<<<8192, 256, 0, stream>>>(x, xbf);
    transpose_cast<<<dim3(128, 32), 256, 0, stream>>>(w1, w1t, 1024, 4096, 4096);

    // G1: u_raw = x @ W1[:, :2048]; xg = x @ W1[:, 2048:]   (256^2, 256 blocks)
    gemm256<bf16, 0><<<dim3(8, 32), 512, 0, stream>>>(
        xbf, w1t, u_raw, 2048, 1024, 1024, 1024, 2048, nullptr);
    gemm256<bf16, 0><<<dim3(8, 32), 512, 0, stream>>>(
        xbf, w1t + (size_t)2048 * 1024, xg, 2048, 1024, 1024, 1024, 2048, nullptr);

    transpose_cast<<<dim3(72, 64), 256, 0, stream>>>(w2, w2t, 2048, 2080, 2304);
    transpose_cast<<<dim3(64, 64), 256, 0, stream>>>(w3, w3t, 2048, 2048, 2048);
    transpose_cast<<<dim3(32, 64), 256, 0, stream>>>(w4, w4t, 2048, 1024, 1024);

    conv_silu<<<8192, 256, 0, stream>>>(u_raw, cw, cb, uc);

    // G3: xdbl = uc @ x_proj_w  (N=2080; Bt rows 2080..2303 zero-padded)
    gemm256<bf16, 0><<<dim3(9, 32), 512, 0, stream>>>(
        uc, w2t, xdbl, 2080, 2048, 2048, 2048, 2080, nullptr);

    for (int chunk = 0; chunk < 2; ++chunk) {
        int d0 = chunk * 1024;
        gemm256<float, 1><<<dim3(4, 32), 512, 0, stream>>>(
            xdbl, w3t + (size_t)d0 * 2048, deltaC, 1024, 2048, 2080, 2048, 1024,
            dtb + d0);
        scan_partial<<<dim3(4, 16, 4), 256, 0, stream>>>(
            deltaC, uc, xdbl, alog, summ_h, summ_a, d0);
        scan_combine<<<dim3(4, 16, 4), 256, 0, stream>>>(summ_h, summ_a);
        scan_final<<<dim3(4, 16, 4), 256, 0, stream>>>(
            deltaC, uc, xdbl, summ_h, alog, dpar, xg, d0);
    }

    // G6: out = y2 @ out_proj_w  (control: proven 128^2 kernel)
    gemm_mfma<float, 0><<<dim3(8, 64), 256, 0, stream>>>(
        xg, w4t, out, 1024, 2048, 2048, 2048, 1024, nullptr);
}

// Round 8
// 597.616 us; speedup vs baseline: 1.4177x; 1.4177x over previous
//
#include <hip/hip_runtime.h>
#include <hip/hip_bf16.h>
#include <cstddef>
#include <cstdint>

// ---------------------------------------------------------------------------
// Mamba S6 layer. B=4, S=2048, D_MODEL=1024, D_STATE=16, D_CONV=3,
// D_INNER=2048, M=8192.
// Round 8: (a) gemm256 retry with __launch_bounds__(512,2) — round-7 spill
// fix (VGPR 92 + 65MB scratch writes) — deployed ONLY on G1a/G1b as bounded
// A/B; all other GEMMs on proven 128^2+swizzle. (b) scan chunks NC=32 (L=64)
// per d-chunk, summaries in d_out-as-scratch (G6 overwrites it last).
// ws layout identical to proven round 6 (152.6 MiB).
// ---------------------------------------------------------------------------

typedef __hip_bfloat16 bf16;
typedef unsigned int u32;
typedef short short8 __attribute__((ext_vector_type(8)));
typedef float f32x4 __attribute__((ext_vector_type(4)));

#define GLOBAL_AS __attribute__((address_space(1)))
#define LDS_AS    __attribute__((address_space(3)))

__device__ __forceinline__ float bf2f(short s) {
    union { float f; u32 u; } x; x.u = ((u32)(unsigned short)s) << 16; return x.f;
}
__device__ __forceinline__ void store_c(float* p, float v) { *p = v; }
__device__ __forceinline__ void store_c(bf16* p, float v)  { *p = __float2bfloat16(v); }

__device__ __forceinline__ int xcd_swizzle(int orig, int nwg) {
    return ((nwg & 7) == 0) ? ((orig & 7) * (nwg >> 3) + (orig >> 3)) : orig;
}

#define BAR()   do { __builtin_amdgcn_s_barrier(); asm volatile("" ::: "memory"); } while (0)
#define VMW4()  asm volatile("s_waitcnt vmcnt(4)" ::: "memory")
#define VMW0()  asm volatile("s_waitcnt vmcnt(0)" ::: "memory")

// ---------------- 256x256 tile, BK=32, 3-slot ring, phase-interleaved -------
// Numerically verified round 7; round-7 perf failure = register spill from
// missing min-waves arg. (512,2): 2 waves/EU -> 256-reg budget, acc in AGPRs.
template <typename TC, int MODE>
__global__ __launch_bounds__(512, 2) void gemm256(
    const bf16* __restrict__ A, const bf16* __restrict__ Bt,
    TC* __restrict__ C, int N, int K, int lda, int ldb, int ldc,
    const float* __restrict__ bias)
{
    __shared__ short As[3][256 * 32];   // 48 KiB
    __shared__ short Bs[3][256 * 32];   // 48 KiB

    const int tid  = threadIdx.x;
    const int lane = tid & 63;
    const int wid  = tid >> 6;
    const int wr   = wid >> 2;
    const int wc   = wid & 3;

    const int gx   = gridDim.x;
    const int wgid = xcd_swizzle(blockIdx.y * gx + blockIdx.x, gx * gridDim.y);
    const int m0   = (wgid / gx) * 256;
    const int n0   = (wgid % gx) * 256;

    const int st_ks = (((tid & 3) ^ ((tid >> 3) & 3)) << 3);
    const int st_r  = tid >> 2;

    const int l15   = lane & 15;
    const int slotp = (((lane >> 4) ^ ((l15 >> 1) & 3)) << 3);

    f32x4 acc[8][4] = {};

    const int KT = K >> 5;

    auto STAGE2 = [&](int sl, int kti, int pr) {
        const int kbase = kti << 5;
        #pragma unroll
        for (int q = 0; q < 2; ++q) {
            int lrow = q * 128 + st_r;
            if (pr == 0) {
                const bf16* g = A + (size_t)(m0 + lrow) * lda + kbase + st_ks;
                __builtin_amdgcn_global_load_lds((const GLOBAL_AS u32*)g,
                    (LDS_AS u32*)(&As[sl][q * 4096 + tid * 8]), 16, 0, 0);
            } else {
                const bf16* g = Bt + (size_t)(n0 + lrow) * ldb + kbase + st_ks;
                __builtin_amdgcn_global_load_lds((const GLOBAL_AS u32*)g,
                    (LDS_AS u32*)(&Bs[sl][q * 4096 + tid * 8]), 16, 0, 0);
            }
        }
    };

    STAGE2(0, 0, 0); STAGE2(0, 0, 1);
    STAGE2(1, 1, 0); STAGE2(1, 1, 1);
    VMW4(); BAR();

    int sl = 0;
    #pragma unroll 1
    for (int kt = 0; kt < KT; ++kt) {
        const bool ds = (kt + 2 < KT);
        const int ns = (sl == 0) ? 2 : sl - 1;
        short8 a[4], b[4];

        #pragma unroll
        for (int j = 0; j < 4; ++j) {
            int row = wc * 64 + j * 16 + l15;
            b[j] = *(const short8*)&Bs[sl][row * 32 + slotp];
        }
        #pragma unroll
        for (int i = 0; i < 4; ++i) {
            int row = wr * 128 + i * 16 + l15;
            a[i] = *(const short8*)&As[sl][row * 32 + slotp];
        }
        if (ds) STAGE2(ns, kt + 2, 0);
        BAR();
        __builtin_amdgcn_s_setprio(1);
        #pragma unroll
        for (int i = 0; i < 4; ++i)
            #pragma unroll
            for (int j = 0; j < 4; ++j)
                acc[i][j] = __builtin_amdgcn_mfma_f32_16x16x32_bf16(
                    a[i], b[j], acc[i][j], 0, 0, 0);
        __builtin_amdgcn_s_setprio(0);
        BAR();

        #pragma unroll
        for (int i = 0; i < 4; ++i) {
            int row = wr * 128 + (4 + i) * 16 + l15;
            a[i] = *(const short8*)&As[sl][row * 32 + slotp];
        }
        if (ds) STAGE2(ns, kt + 2, 1);
        BAR();
        __builtin_amdgcn_s_setprio(1);
        #pragma unroll
        for (int i = 0; i < 4; ++i)
            #pragma unroll
            for (int j = 0; j < 4; ++j)
                acc[4 + i][j] = __builtin_amdgcn_mfma_f32_16x16x32_bf16(
                    a[i], b[j], acc[4 + i][j], 0, 0, 0);
        __builtin_amdgcn_s_setprio(0);
        if (ds) { VMW4(); } else { VMW0(); }
        BAR();
        sl = (sl == 2) ? 0 : sl + 1;
    }

    const int cl = lane & 15;
    const int rq = lane >> 4;
    #pragma unroll
    for (int i = 0; i < 8; ++i) {
        #pragma unroll
        for (int j = 0; j < 4; ++j) {
            int gc = n0 + wc * 64 + j * 16 + cl;
            if (gc >= N) continue;
            float bv = (MODE == 1) ? bias[gc] : 0.f;
            #pragma unroll
            for (int f = 0; f < 4; ++f) {
                int gr = m0 + wr * 128 + i * 16 + rq * 4 + f;
                float v = acc[i][j][f];
                if (MODE == 1) {
                    v += bv;
                    v = fmaxf(v, 0.f) + log1pf(__expf(-fabsf(v)));
                }
                store_c(&C[(size_t)gr * ldc + gc], v);
            }
        }
    }
}

// ---------------- 128x128 tile GEMM (m97 structure) + XCD swizzle -----------
template <typename TC, int MODE>
__global__ __launch_bounds__(256) void gemm_mfma(
    const bf16* __restrict__ A, const bf16* __restrict__ Bt,
    TC* __restrict__ C, int N, int K, int lda, int ldb, int ldc,
    const float* __restrict__ bias)
{
    __shared__ short As[128 * 64];
    __shared__ short Bs[128 * 64];

    const int tid  = threadIdx.x;
    const int lane = tid & 63;
    const int w    = tid >> 6;
    const int wr   = w >> 1, wc = w & 1;

    const int gx   = gridDim.x;
    const int wgid = xcd_swizzle(blockIdx.y * gx + blockIdx.x, gx * gridDim.y);
    const int m0   = (wgid / gx) * 128;
    const int n0   = (wgid % gx) * 128;

    const int lr = tid >> 3;
    const int s8 = tid & 7;

    f32x4 acc[4][4] = {};

    const int KT = K >> 6;
    for (int kt = 0; kt < KT; ++kt) {
        const int k0 = kt << 6;
        #pragma unroll
        for (int q = 0; q < 4; ++q) {
            int r = q * 32 + lr;
            int ks = (s8 ^ (r & 7)) * 8;
            const bf16* ga = A + (size_t)(m0 + r) * lda + k0 + ks;
            __builtin_amdgcn_global_load_lds((const GLOBAL_AS u32*)ga,
                (LDS_AS u32*)(As + q * 2048 + tid * 8), 16, 0, 0);
        }
        #pragma unroll
        for (int q = 0; q < 4; ++q) {
            int r = q * 32 + lr;
            int ks = (s8 ^ (r & 7)) * 8;
            const bf16* gb = Bt + (size_t)(n0 + r) * ldb + k0 + ks;
            __builtin_amdgcn_global_load_lds((const GLOBAL_AS u32*)gb,
                (LDS_AS u32*)(Bs + q * 2048 + tid * 8), 16, 0, 0);
        }
        __syncthreads();
        #pragma unroll
        for (int s = 0; s < 2; ++s) {
            short8 af[4], bfr[4];
            #pragma unroll
            for (int i = 0; i < 4; ++i) {
                int r = wr * 64 + i * 16 + (lane & 15);
                int slot = ((s << 2) + (lane >> 4)) ^ (r & 7);
                af[i] = *(const short8*)&As[r * 64 + slot * 8];
            }
            #pragma unroll
            for (int j = 0; j < 4; ++j) {
                int r = wc * 64 + j * 16 + (lane & 15);
                int slot = ((s << 2) + (lane >> 4)) ^ (r & 7);
                bfr[j] = *(const short8*)&Bs[r * 64 + slot * 8];
            }
            #pragma unroll
            for (int i = 0; i < 4; ++i)
                #pragma unroll
                for (int j = 0; j < 4; ++j)
                    acc[i][j] = __builtin_amdgcn_mfma_f32_16x16x32_bf16(
                        af[i], bfr[j], acc[i][j], 0, 0, 0);
        }
        __syncthreads();
    }

    const int cl = lane & 15;
    const int rq = lane >> 4;
    #pragma unroll
    for (int i = 0; i < 4; ++i) {
        #pragma unroll
        for (int j = 0; j < 4; ++j) {
            int gc = n0 + wc * 64 + j * 16 + cl;
            if (gc >= N) continue;
            float bv = (MODE == 1) ? bias[gc] : 0.f;
            #pragma unroll
            for (int f = 0; f < 4; ++f) {
                int gr = m0 + wr * 64 + i * 16 + rq * 4 + f;
                float v = acc[i][j][f];
                if (MODE == 1) {
                    v += bv;
                    v = fmaxf(v, 0.f) + log1pf(__expf(-fabsf(v)));
                }
                store_c(&C[(size_t)gr * ldc + gc], v);
            }
        }
    }
}

// wt[n][k] = (bf16) w[k][n]; rows n in [Nsrc,Npad) zero-filled.
__global__ __launch_bounds__(256) void transpose_cast(
    const float* __restrict__ src, bf16* __restrict__ dst,
    int K, int Nsrc, int Npad)
{
    __shared__ float t[32][33];
    int n0 = blockIdx.x * 32, k0 = blockIdx.y * 32;
    int lx = threadIdx.x & 31, ly = threadIdx.x >> 5;
    #pragma unroll
    for (int i = 0; i < 4; ++i) {
        int k = k0 + ly + 8 * i, n = n0 + lx;
        t[ly + 8 * i][lx] = (n < Nsrc) ? src[(size_t)k * Nsrc + n] : 0.f;
    }
    __syncthreads();
    #pragma unroll
    for (int i = 0; i < 4; ++i) {
        int n = n0 + ly + 8 * i;
        if (n < Npad) dst[(size_t)n * K + k0 + lx] = __float2bfloat16(t[lx][ly + 8 * i]);
    }
}

__global__ __launch_bounds__(256) void cast_x_kernel(
    const float* __restrict__ x, bf16* __restrict__ xb)
{
    int i = blockIdx.x * 256 + threadIdx.x;
    float4 v = ((const float4*)x)[i];
    alignas(8) bf16 h[4] = {__float2bfloat16(v.x), __float2bfloat16(v.y),
                            __float2bfloat16(v.z), __float2bfloat16(v.w)};
    ((ushort4*)xb)[i] = *(ushort4*)h;
}

// depthwise conv w=3 SAME per-sequence + bias + SiLU; 8 channels/thread.
__global__ __launch_bounds__(256) void conv_silu(
    const bf16* __restrict__ ur, const float* __restrict__ cw,
    const float* __restrict__ cb, bf16* __restrict__ uc)
{
    int idx = blockIdx.x * 256 + threadIdx.x;
    int d8 = idx & 255;
    int m  = idx >> 8;
    int s  = m & 2047;
    int d0 = d8 << 3;

    short8 z = {0, 0, 0, 0, 0, 0, 0, 0};
    short8 u0 = *(const short8*)&ur[(size_t)m * 2048 + d0];
    short8 um = (s > 0)    ? *(const short8*)&ur[(size_t)(m - 1) * 2048 + d0] : z;
    short8 up = (s < 2047) ? *(const short8*)&ur[(size_t)(m + 1) * 2048 + d0] : z;

    float wv[24];
    #pragma unroll
    for (int q = 0; q < 6; ++q) *(float4*)&wv[q * 4] = ((const float4*)(cw + d0 * 3))[q];
    float bv[8];
    *(float4*)&bv[0] = ((const float4*)(cb + d0))[0];
    *(float4*)&bv[4] = ((const float4*)(cb + d0))[1];

    alignas(16) bf16 o[8];
    #pragma unroll
    for (int i = 0; i < 8; ++i) {
        float acc = bv[i] + wv[i * 3] * bf2f(um[i]) + wv[i * 3 + 1] * bf2f(u0[i])
                  + wv[i * 3 + 2] * bf2f(up[i]);
        float sig = 1.f / (1.f + __expf(-acc));
        o[i] = __float2bfloat16(acc * sig);
    }
    *(short8*)&uc[(size_t)m * 2048 + d0] = *(short8*)o;
}

// ---- chunk-parallel selective scan: NC=32 chunks of L=64 per d-chunk -------
// summaries layout: [b][c][n][dl], idx = (((b*32+c)*16+n)<<10) + dl
__global__ __launch_bounds__(256) void scan_partial(
    const float* __restrict__ deltaC,
    const bf16* __restrict__ uc,
    const bf16* __restrict__ xdbl,
    const float* __restrict__ A_log,
    float* __restrict__ hout, float* __restrict__ aprod, int d0)
{
    int dl = blockIdx.x * 256 + threadIdx.x;   // grid.x=4 -> dl<1024
    int c  = blockIdx.y;                       // 32 chunks
    int b  = blockIdx.z;
    int d  = d0 + dl;

    float a[16];
    #pragma unroll
    for (int n = 0; n < 16; ++n) a[n] = -__expf(A_log[d * 16 + n]);
    float hl[16] = {};
    float P[16];
    #pragma unroll
    for (int n = 0; n < 16; ++n) P[n] = 1.f;

    size_t mbase = (size_t)b * 2048 + c * 64;
    for (int s = 0; s < 64; ++s) {
        size_t m = mbase + s;
        float dv = deltaC[m * 1024 + dl];
        float uv = bf2f(*(const short*)&uc[m * 2048 + d]);
        const short8* bp = (const short8*)&xdbl[m * 2080 + 2048];
        short8 B0 = bp[0], B1 = bp[1];
        float du = dv * uv;
        #pragma unroll
        for (int n = 0; n < 16; ++n) {
            float al = __expf(dv * a[n]);
            float Bn = bf2f(n < 8 ? B0[n] : B1[n - 8]);
            hl[n] = al * hl[n] + du * Bn;
            P[n] *= al;
        }
    }
    #pragma unroll
    for (int n = 0; n < 16; ++n) {
        int idx = (((b * 32 + c) * 16 + n) << 10) + dl;
        hout[idx]  = hl[n];
        aprod[idx] = P[n];
    }
}

__global__ __launch_bounds__(256) void scan_combine(
    float* hout, const float* __restrict__ aprod)
{
    int dl = blockIdx.x * 256 + threadIdx.x;   // grid.x=4
    int n  = blockIdx.y;                       // 16
    int b  = blockIdx.z;                       // 4
    float H = 0.f;
    for (int c = 0; c < 32; ++c) {
        int idx = (((b * 32 + c) * 16 + n) << 10) + dl;
        float he = hout[idx];
        float Pp = aprod[idx];
        hout[idx] = H;            // h at chunk start
        H = Pp * H + he;
    }
}

__global__ __launch_bounds__(256) void scan_final(
    const float* __restrict__ deltaC,
    const bf16* __restrict__ uc,
    const bf16* __restrict__ xdbl,
    const float* __restrict__ hin,
    const float* __restrict__ A_log, const float* __restrict__ D_param,
    bf16* ygate, int d0)
{
    int dl = blockIdx.x * 256 + threadIdx.x;
    int c  = blockIdx.y;
    int b  = blockIdx.z;
    int d  = d0 + dl;

    float a[16], H[16];
    #pragma unroll
    for (int n = 0; n < 16; ++n) {
        a[n] = -__expf(A_log[d * 16 + n]);
        H[n] = hin[(((b * 32 + c) * 16 + n) << 10) + dl];
    }
    float Dp = D_param[d];
    float hl[16] = {};
    float P[16];
    #pragma unroll
    for (int n = 0; n < 16; ++n) P[n] = 1.f;

    size_t mbase = (size_t)b * 2048 + c * 64;
    float xg_cur = bf2f(*(const short*)&ygate[mbase * 2048 + d]);

    for (int s = 0; s < 64; ++s) {
        size_t m = mbase + s;
        float dv = deltaC[m * 1024 + dl];
        float uv = bf2f(*(const short*)&uc[m * 2048 + d]);
        const short8* bp = (const short8*)&xdbl[m * 2080 + 2048];
        short8 B0 = bp[0], B1 = bp[1], C0 = bp[2], C1 = bp[3];
        float du = dv * uv;
        float y = 0.f;
        #pragma unroll
        for (int n = 0; n < 16; ++n) {
            float al = __expf(dv * a[n]);
            float Bn = bf2f(n < 8 ? B0[n] : B1[n - 8]);
            float Cn = bf2f(n < 8 ? C0[n] : C1[n - 8]);
            hl[n] = al * hl[n] + du * Bn;
            P[n] *= al;
            float ht = fmaf(P[n], H[n], hl[n]);
            y = fmaf(ht, Cn, y);
        }
        float xgv = xg_cur;
        if (s < 63) xg_cur = bf2f(*(const short*)&ygate[(m + 1) * 2048 + d]);
        float sig = 1.f / (1.f + __expf(-xgv));
        float y2 = (y + uv * Dp) * (xgv * sig);
        ygate[m * 2048 + d] = __float2bfloat16(y2);
    }
}

extern "C" void kernel_launch(void* const* d_in, const int* in_sizes, int n_in,
                              void* d_out, int out_size, void* d_ws, size_t ws_size,
                              hipStream_t stream) {
    const float* x    = (const float*)d_in[0];
    const float* w1   = (const float*)d_in[1];   // [1024,4096]
    const float* cw   = (const float*)d_in[2];   // [2048,1,3]
    const float* cb   = (const float*)d_in[3];   // [2048]
    const float* w2   = (const float*)d_in[4];   // [2048,2080]
    const float* w3   = (const float*)d_in[5];   // [2048,2048]
    const float* dtb  = (const float*)d_in[6];   // [2048]
    const float* w4   = (const float*)d_in[7];   // [2048,1024]
    const float* alog = (const float*)d_in[8];   // [2048,16]
    const float* dpar = (const float*)d_in[9];   // [2048]
    float* out = (float*)d_out;

    // ws layout (152.5 MiB, proven round 6). Scan summaries live in d_out
    // (8+8 MiB per chunk; G6 fully overwrites d_out afterwards).
    const size_t MB = 1u << 20;
    const size_t needed = 120 * MB + (size_t)8192 * 2080 * 2;
    if (ws_size < needed) return;

    char* p = (char*)d_ws;
    bf16*  xbf    = (bf16*)(p);
    bf16*  w1t    = (bf16*)(p + 16 * MB);
    bf16*  u_raw  = (bf16*)(p + 24 * MB);
    bf16*  w2t    = (bf16*)(p);                       // [2176,2048] 8.5 MiB
    bf16*  w3t    = (bf16*)(p + 8912896);
    bf16*  w4t    = (bf16*)(p + 8912896 + 8388608);
    float* deltaC = (float*)(p + 24 * MB);
    bf16*  xg     = (bf16*)(p + 56 * MB);
    bf16*  uc     = (bf16*)(p + 88 * MB);
    bf16*  xdbl   = (bf16*)(p + 120 * MB);

    float* summ_h = out;                   // 8 MiB used (of 32)
    float* summ_a = out + (size_t)2 * 1024 * 1024;

    cast_x_kernel<<<8192, 256, 0, stream>>>(x, xbf);
    transpose_cast<<<dim3(128, 32), 256, 0, stream>>>(w1, w1t, 1024, 4096, 4096);

    // G1 (A/B experiment): 256^2 pipelined kernel, spill-fixed (512,2).
    gemm256<bf16, 0><<<dim3(8, 32), 512, 0, stream>>>(
        xbf, w1t, u_raw, 2048, 1024, 1024, 1024, 2048, nullptr);
    gemm256<bf16, 0><<<dim3(8, 32), 512, 0, stream>>>(
        xbf, w1t + (size_t)2048 * 1024, xg, 2048, 1024, 1024, 1024, 2048, nullptr);

    transpose_cast<<<dim3(68, 64), 256, 0, stream>>>(w2, w2t, 2048, 2080, 2176);
    transpose_cast<<<dim3(64, 64), 256, 0, stream>>>(w3, w3t, 2048, 2048, 2048);
    transpose_cast<<<dim3(32, 64), 256, 0, stream>>>(w4, w4t, 2048, 1024, 1024);

    conv_silu<<<8192, 256, 0, stream>>>(u_raw, cw, cb, uc);

    // G3: xdbl = uc @ x_proj_w  (proven 128^2; Bt rows 2080..2175 zero)
    gemm_mfma<bf16, 0><<<dim3(17, 64), 256, 0, stream>>>(
        uc, w2t, xdbl, 2080, 2048, 2048, 2048, 2080, nullptr);

    for (int chunk = 0; chunk < 2; ++chunk) {
        int d0 = chunk * 1024;
        gemm_mfma<float, 1><<<dim3(8, 64), 256, 0, stream>>>(
            xdbl, w3t + (size_t)d0 * 2048, deltaC, 1024, 2048, 2080, 2048, 1024,
            dtb + d0);
        scan_partial<<<dim3(4, 32, 4), 256, 0, stream>>>(
            deltaC, uc, xdbl, alog, summ_h, summ_a, d0);
        scan_combine<<<dim3(4, 16, 4), 256, 0, stream>>>(summ_h, summ_a);
        scan_final<<<dim3(4, 32, 4), 256, 0, stream>>>(
            deltaC, uc, xdbl, summ_h, alog, dpar, xg, d0);
    }

    // G6: out = y2 @ out_proj_w  (fully overwrites d_out incl. summ scratch)
    gemm_mfma<float, 0><<<dim3(8, 64), 256, 0, stream>>>(
        xg, w4t, out, 1024, 2048, 2048, 2048, 1024, nullptr);
}